// Round 2
// baseline (373.791 us; speedup 1.0000x reference)
//
#include <hip/hip_runtime.h>

#define N_NODES 50000
#define E_EDGES 800000
#define IN_DIM 256
#define H_HEADS 4
#define F_OUT 64
#define EF_DIM 64
#define NT_TYPES 8
#define SLOPE 0.2f
#define HF 256  /* H*F */

typedef __attribute__((ext_vector_type(8))) short short8;
typedef __attribute__((ext_vector_type(4))) float f32x4;
typedef unsigned short ushort_t;
typedef unsigned long long u64;

// workspace layout (float element offsets)
#define FEATBF_OFF 0          /* N*HF bf16 = 6.4M floats */
#define EL_OFF   6400000
#define ER_OFF   6600000
#define EE_OFF   6800000
#define BT_OFF   6800064      /* 256x256 bf16 = 32768 floats */
#define INT_OFF  6832832
// int offsets within int region
#define DEG_IOFF     0        /* 50,000 */
#define CURSOR_IOFF  50000    /* 50,000 (adjacent: zeroed together) */
#define RL_IOFF      100000   /* 50,000: per-node exclusive prefix within 256-chunk */
#define PK_IOFF      150008   /* packed edges: 800,000 u64 (8B aligned) */
#define BO_IOFF      1750008  /* 256: chunk-sum exclusive prefix (196 used) */

#define NBLK_GEMM 782         /* ceil(50000/64) */
#define NBLK_E4   782         /* ceil(800000/4/256): int4 edge kernels */
#define NCHUNK    196         /* ceil(50000/256) */

// GEMM block distribution across the hist->scan->scatter chain
#define G2   312
#define G3A  120
#define G3B  100
#define G4   250
#define G2_BASE   0
#define G3A_BASE  312
#define G3B_BASE  432
#define G4_BASE   532   /* 532+250 = 782 */

__device__ __forceinline__ ushort_t f2bf(float f) {
    unsigned u = __float_as_uint(f);
    u += 0x7fffu + ((u >> 16) & 1u);   // round-nearest-even
    return (ushort_t)(u >> 16);
}
__device__ __forceinline__ float bf2f(ushort_t b) {
    return __uint_as_float(((unsigned)b) << 16);
}

// ======================= K1: ee + cast_w + zero(deg,cursor) =======================
__global__ __launch_bounds__(256) void k1_prep(
    const float* __restrict__ edge_emb, const float* __restrict__ fc_e_w,
    const float* __restrict__ attn_e, const float* __restrict__ fc_w,
    float* __restrict__ ee, ushort_t* __restrict__ Bt, int* __restrict__ zero_region)
{
    const int b = blockIdx.x;
    if (b == 0) {
        const int c = threadIdx.x;
        const float ae = attn_e[c];
        const int lane = c & 63, h = c >> 6;
        for (int ty = 0; ty < NT_TYPES; ty++) {
            float v = 0.f;
            #pragma unroll 8
            for (int k = 0; k < EF_DIM; k++)
                v = fmaf(edge_emb[ty * EF_DIM + k], fc_e_w[k * (H_HEADS * EF_DIM) + c], v);
            float contrib = v * ae;
            #pragma unroll
            for (int m = 32; m >= 1; m >>= 1) contrib += __shfl_xor(contrib, m);
            if (lane == 0) ee[ty * H_HEADS + h] = contrib;
        }
    } else if (b <= 256) {
        const int k = b - 1, c = threadIdx.x;
        Bt[(size_t)c * 256 + k] = f2bf(fc_w[(size_t)k * 256 + c]);
    } else {
        const int idx = (b - 257) * 256 + threadIdx.x;
        if (idx < 2 * N_NODES) zero_region[idx] = 0;   // deg + cursor adjacent
    }
}

// ======================= GEMM body (MFMA bf16) =======================
__device__ __forceinline__ void gemm_body(
    const float* __restrict__ nfeat, const ushort_t* __restrict__ Bt,
    const float* __restrict__ attn_l, const float* __restrict__ attn_r,
    ushort_t* __restrict__ feat, float* __restrict__ el, float* __restrict__ er,
    int blk)
{
    const int w    = threadIdx.x >> 6;
    const int lane = threadIdx.x & 63;
    const int n16  = lane & 15;
    const int quad = lane >> 4;
    const int row0 = blk * 64;

    f32x4 acc[4][4];
    #pragma unroll
    for (int rt = 0; rt < 4; rt++)
        #pragma unroll
        for (int ct = 0; ct < 4; ct++)
            acc[rt][ct] = (f32x4){0.f, 0.f, 0.f, 0.f};

    for (int kb = 0; kb < IN_DIM; kb += 32) {
        short8 a[4], b[4];
        #pragma unroll
        for (int rt = 0; rt < 4; rt++) {
            int r = row0 + rt * 16 + n16;
            r = r < N_NODES ? r : N_NODES - 1;
            const float* p = nfeat + (size_t)r * IN_DIM + kb + quad * 8;
            const float4 v0 = *(const float4*)p;
            const float4 v1 = *(const float4*)(p + 4);
            short8 t;
            t[0] = (short)f2bf(v0.x); t[1] = (short)f2bf(v0.y);
            t[2] = (short)f2bf(v0.z); t[3] = (short)f2bf(v0.w);
            t[4] = (short)f2bf(v1.x); t[5] = (short)f2bf(v1.y);
            t[6] = (short)f2bf(v1.z); t[7] = (short)f2bf(v1.w);
            a[rt] = t;
        }
        #pragma unroll
        for (int ct = 0; ct < 4; ct++) {
            const int c = w * 64 + ct * 16 + n16;
            b[ct] = *(const short8*)(Bt + (size_t)c * 256 + kb + quad * 8);
        }
        #pragma unroll
        for (int rt = 0; rt < 4; rt++)
            #pragma unroll
            for (int ct = 0; ct < 4; ct++)
                acc[rt][ct] = __builtin_amdgcn_mfma_f32_16x16x32_bf16(a[rt], b[ct], acc[rt][ct], 0, 0, 0);
    }

    float alv[4], arv[4];
    #pragma unroll
    for (int ct = 0; ct < 4; ct++) {
        alv[ct] = attn_l[w * 64 + ct * 16 + n16];
        arv[ct] = attn_r[w * 64 + ct * 16 + n16];
    }
    #pragma unroll
    for (int rt = 0; rt < 4; rt++) {
        #pragma unroll
        for (int reg = 0; reg < 4; reg++) {
            const int row = row0 + rt * 16 + quad * 4 + reg;
            const bool ok = row < N_NODES;
            float pl = 0.f, pr = 0.f;
            #pragma unroll
            for (int ct = 0; ct < 4; ct++) {
                const float v = acc[rt][ct][reg];
                if (ok) feat[(size_t)row * HF + w * 64 + ct * 16 + n16] = f2bf(v);
                pl = fmaf(v, alv[ct], pl);
                pr = fmaf(v, arv[ct], pr);
            }
            #pragma unroll
            for (int m = 8; m >= 1; m >>= 1) {
                pl += __shfl_xor(pl, m);
                pr += __shfl_xor(pr, m);
            }
            if (n16 == 0 && ok) {
                el[row * H_HEADS + w] = pl;
                er[row * H_HEADS + w] = pr;
            }
        }
    }
}

// ======================= K2: int4 histogram || GEMM chunk =======================
__global__ __launch_bounds__(256) void k2_hist_gemm(
    const float* __restrict__ nfeat, const ushort_t* __restrict__ Bt,
    const float* __restrict__ attn_l, const float* __restrict__ attn_r,
    ushort_t* __restrict__ feat, float* __restrict__ el, float* __restrict__ er,
    const int* __restrict__ dst, int* __restrict__ deg)
{
    if (blockIdx.x < NBLK_E4) {
        const int t = blockIdx.x * 256 + threadIdx.x;
        if (t < E_EDGES / 4) {
            const int4 d4 = ((const int4*)dst)[t];
            atomicAdd(deg + d4.x, 1);
            atomicAdd(deg + d4.y, 1);
            atomicAdd(deg + d4.z, 1);
            atomicAdd(deg + d4.w, 1);
        }
    } else {
        gemm_body(nfeat, Bt, attn_l, attn_r, feat, el, er,
                  G2_BASE + (int)blockIdx.x - NBLK_E4);
    }
}

// ======================= K3a: per-chunk local scan || GEMM chunk =======================
__global__ __launch_bounds__(256) void scanA_gemm(
    const float* __restrict__ nfeat, const ushort_t* __restrict__ Bt,
    const float* __restrict__ attn_l, const float* __restrict__ attn_r,
    ushort_t* __restrict__ feat, float* __restrict__ el, float* __restrict__ er,
    const int* __restrict__ deg, int* __restrict__ rl, int* __restrict__ bo)
{
    if (blockIdx.x < NCHUNK) {
        __shared__ int sm[256];
        const int c = blockIdx.x, t = threadIdx.x;
        const int g = c * 256 + t;
        const int v = (g < N_NODES) ? deg[g] : 0;
        sm[t] = v;
        __syncthreads();
        int val = v;
        #pragma unroll
        for (int o = 1; o < 256; o <<= 1) {
            int x = (t >= o) ? sm[t - o] : 0;
            __syncthreads();
            val += x;
            sm[t] = val;
            __syncthreads();
        }
        if (g < N_NODES) rl[g] = val - v;   // exclusive within chunk
        if (t == 255) bo[c] = val;          // chunk total
    } else {
        gemm_body(nfeat, Bt, attn_l, attn_r, feat, el, er,
                  G3A_BASE + (int)blockIdx.x - NCHUNK);
    }
}

// ======================= K3b: scan chunk sums || GEMM chunk =======================
__global__ __launch_bounds__(256) void scanB_gemm(
    const float* __restrict__ nfeat, const ushort_t* __restrict__ Bt,
    const float* __restrict__ attn_l, const float* __restrict__ attn_r,
    ushort_t* __restrict__ feat, float* __restrict__ el, float* __restrict__ er,
    int* __restrict__ bo)
{
    if (blockIdx.x == 0) {
        __shared__ int sm[256];
        const int t = threadIdx.x;
        const int v = (t < NCHUNK) ? bo[t] : 0;
        sm[t] = v;
        __syncthreads();
        int val = v;
        #pragma unroll
        for (int o = 1; o < 256; o <<= 1) {
            int x = (t >= o) ? sm[t - o] : 0;
            __syncthreads();
            val += x;
            sm[t] = val;
            __syncthreads();
        }
        if (t < NCHUNK) bo[t] = val - v;    // exclusive chunk offsets
    } else {
        gemm_body(nfeat, Bt, attn_l, attn_r, feat, el, er,
                  G3B_BASE + (int)blockIdx.x - 1);
    }
}

// ======================= K4: int4 scatter || GEMM chunk =======================
__global__ __launch_bounds__(256) void k4_scatter_gemm(
    const float* __restrict__ nfeat, const ushort_t* __restrict__ Bt,
    const float* __restrict__ attn_l, const float* __restrict__ attn_r,
    ushort_t* __restrict__ feat, float* __restrict__ el, float* __restrict__ er,
    const int* __restrict__ src, const int* __restrict__ dst, const int* __restrict__ etype,
    const int* __restrict__ rl, const int* __restrict__ bo,
    int* __restrict__ cursor, u64* __restrict__ pk)
{
    if (blockIdx.x < NBLK_E4) {
        const int t = blockIdx.x * 256 + threadIdx.x;
        if (t < E_EDGES / 4) {
            const int4 s4 = ((const int4*)src)[t];
            const int4 d4 = ((const int4*)dst)[t];
            const int4 e4 = ((const int4*)etype)[t];
            const int eb = t * 4;
            int pos;
            pos = bo[d4.x >> 8] + rl[d4.x] + atomicAdd(cursor + d4.x, 1);
            pk[pos] = (u64)s4.x | ((u64)e4.x << 16) | ((u64)(eb + 0) << 32);
            pos = bo[d4.y >> 8] + rl[d4.y] + atomicAdd(cursor + d4.y, 1);
            pk[pos] = (u64)s4.y | ((u64)e4.y << 16) | ((u64)(eb + 1) << 32);
            pos = bo[d4.z >> 8] + rl[d4.z] + atomicAdd(cursor + d4.z, 1);
            pk[pos] = (u64)s4.z | ((u64)e4.z << 16) | ((u64)(eb + 2) << 32);
            pos = bo[d4.w >> 8] + rl[d4.w] + atomicAdd(cursor + d4.w, 1);
            pk[pos] = (u64)s4.w | ((u64)e4.w << 16) | ((u64)(eb + 3) << 32);
        }
    } else {
        gemm_body(nfeat, Bt, attn_l, attn_r, feat, el, er,
                  G4_BASE + (int)blockIdx.x - NBLK_E4);
    }
}

// ======================= K5: wave-per-node softmax + aggregation (v6) =======================
// Wave layout: 64 lanes = 4 head-groups x 16 edge-slots. No __syncthreads in main path.
__global__ __launch_bounds__(256) void agg_kernel(
    const u64* __restrict__ pk, const int* __restrict__ rl, const int* __restrict__ bo,
    const int* __restrict__ degarr,
    const float* __restrict__ el, const float* __restrict__ er,
    const float* __restrict__ ee, const ushort_t* __restrict__ feat,
    float* __restrict__ a_out, float* __restrict__ rst)
{
    const int wid  = threadIdx.x >> 6;              // wave in block
    const int d    = blockIdx.x * 4 + wid;          // node (12500*4 = 50000 exactly)
    const int lane = threadIdx.x & 63;
    const int h    = lane >> 4;                     // head group 0..3
    const int l    = lane & 15;                     // slot in group

    __shared__ __align__(16) ushort_t sS[4][256];   // src per edge (per wave)
    __shared__ __align__(16) float    aB[4][256 * 4]; // [edge][head] exp values (per wave)

    if (d >= N_NODES) return;
    ushort_t* sSw = sS[wid];
    float*    aBw = aB[wid];
    const uint2* fb = (const uint2*)feat;

    const int off = bo[d >> 8] + rl[d];
    const int deg = degarr[d];
    const float erh = er[d * 4 + h];

    if (deg <= 256) {
        const int nch  = (deg + 15) >> 4;
        const int degP = nch << 4;

        // Phase A: leaky scores -> aB raw; running max in reg
        float m = -INFINITY;
        for (int c = 0; c < nch; c++) {
            const int e = c * 16 + l;
            float v = -INFINITY;
            if (e < deg) {
                const u64 p = pk[off + e];
                const int s  = (int)(p & 0xffffu);
                const int ty = (int)((p >> 16) & 0xffu);
                if (h == 0) sSw[e] = (ushort_t)s;
                v = el[s * 4 + h] + erh + ee[ty * 4 + h];
                v = v > 0.f ? v : SLOPE * v;
                aBw[e * 4 + h] = v;
            }
            m = fmaxf(m, v);
        }
        m = fmaxf(m, __shfl_xor(m, 1));
        m = fmaxf(m, __shfl_xor(m, 2));
        m = fmaxf(m, __shfl_xor(m, 4));
        m = fmaxf(m, __shfl_xor(m, 8));

        // Phase B: exp in place (pads -> 0, pad src -> 0), running sum
        float s = 0.f;
        for (int c = 0; c < nch; c++) {
            const int e = c * 16 + l;
            float ev = 0.f;
            if (e < deg) ev = __expf(aBw[e * 4 + h] - m);
            else if (h == 0) sSw[e] = 0;            // pad -> row 0, weight 0
            aBw[e * 4 + h] = ev;
            s += ev;
        }
        s += __shfl_xor(s, 1);
        s += __shfl_xor(s, 2);
        s += __shfl_xor(s, 4);
        s += __shfl_xor(s, 8);
        const float inv = (deg > 0) ? 1.f / s : 0.f;

        // fence: make this wave's LDS writes visible to cross-lane reads below
        asm volatile("s_waitcnt lgkmcnt(0)" ::: "memory");

        // broadcast per-head inv to everyone (for the float4 a_out writer)
        const float inv0 = __shfl(inv, 0);
        const float inv1 = __shfl(inv, 16);
        const float inv2 = __shfl(inv, 32);
        const float inv3 = __shfl(inv, 48);

        // Phase C: a_out — one float4 per edge (group 0 only)
        if (h == 0) {
            for (int c = 0; c < nch; c++) {
                const int e = c * 16 + l;
                if (e < deg) {
                    const u64 p = pk[off + e];          // L2-hot reload for eid
                    const int eid = (int)(p >> 32);
                    const float4 t = *(const float4*)(aBw + e * 4);
                    float4 av;
                    av.x = t.x * inv0;
                    av.y = t.y * inv1;
                    av.z = t.z * inv2;
                    av.w = t.w * inv3;
                    *(float4*)(a_out + (size_t)eid * 4) = av;
                }
            }
        }

        // Phase D: gather. lane (h,l) accumulates f = l*4 .. l*4+3 of head h.
        float4 acc = {0.f, 0.f, 0.f, 0.f};
        const int col = h * 16 + l;                     // uint2 column in feat row
        for (int e0 = 0; e0 < degP; e0 += 4) {
            #pragma unroll
            for (int j = 0; j < 4; j++) {
                const int e = e0 + j;
                const int sn = (int)sSw[e];             // broadcast
                const float aw = aBw[e * 4 + h];        // 4-bank broadcast
                const uint2 u = fb[(size_t)sn * 64 + col];
                acc.x = fmaf(aw, __uint_as_float(u.x << 16),         acc.x);
                acc.y = fmaf(aw, __uint_as_float(u.x & 0xffff0000u), acc.y);
                acc.z = fmaf(aw, __uint_as_float(u.y << 16),         acc.z);
                acc.w = fmaf(aw, __uint_as_float(u.y & 0xffff0000u), acc.w);
            }
        }
        acc.x *= inv; acc.y *= inv; acc.z *= inv; acc.w *= inv;
        *(float4*)(rst + (size_t)d * HF + h * 64 + l * 4) = acc;
    } else {
        // fallback: deg > 256 (never for this input; correctness only)
        float m = -INFINITY;
        for (int i = l; i < deg; i += 16) {
            const u64 p = pk[off + i];
            float v = el[(int)(p & 0xffffu) * 4 + h] + erh + ee[(int)((p >> 16) & 0xffu) * 4 + h];
            v = v > 0.f ? v : SLOPE * v;
            m = fmaxf(m, v);
        }
        m = fmaxf(m, __shfl_xor(m, 1));
        m = fmaxf(m, __shfl_xor(m, 2));
        m = fmaxf(m, __shfl_xor(m, 4));
        m = fmaxf(m, __shfl_xor(m, 8));
        float s = 0.f;
        for (int i = l; i < deg; i += 16) {
            const u64 p = pk[off + i];
            float v = el[(int)(p & 0xffffu) * 4 + h] + erh + ee[(int)((p >> 16) & 0xffu) * 4 + h];
            v = v > 0.f ? v : SLOPE * v;
            s += __expf(v - m);
        }
        s += __shfl_xor(s, 1);
        s += __shfl_xor(s, 2);
        s += __shfl_xor(s, 4);
        s += __shfl_xor(s, 8);
        const float inv = 1.f / s;
        for (int i = l; i < deg; i += 16) {
            const u64 p = pk[off + i];
            const int sn = (int)(p & 0xffffu);
            float v = el[sn * 4 + h] + erh + ee[(int)((p >> 16) & 0xffu) * 4 + h];
            v = v > 0.f ? v : SLOPE * v;
            a_out[(int)(p >> 32) * 4 + h] = __expf(v - m) * inv;
        }
        float4 acc = {0.f, 0.f, 0.f, 0.f};
        const int col = h * 16 + l;
        for (int e = 0; e < deg; e++) {
            const u64 p = pk[off + e];
            const int sn = (int)(p & 0xffffu);
            float v = el[sn * 4 + h] + erh + ee[(int)((p >> 16) & 0xffu) * 4 + h];
            v = v > 0.f ? v : SLOPE * v;
            const float aw = __expf(v - m) * inv;
            const uint2 u = fb[(size_t)sn * 64 + col];
            acc.x = fmaf(aw, __uint_as_float(u.x << 16),         acc.x);
            acc.y = fmaf(aw, __uint_as_float(u.x & 0xffff0000u), acc.y);
            acc.z = fmaf(aw, __uint_as_float(u.y << 16),         acc.z);
            acc.w = fmaf(aw, __uint_as_float(u.y & 0xffff0000u), acc.w);
        }
        *(float4*)(rst + (size_t)d * HF + h * 64 + l * 4) = acc;
    }
}

extern "C" void kernel_launch(void* const* d_in, const int* in_sizes, int n_in,
                              void* d_out, int out_size, void* d_ws, size_t ws_size,
                              hipStream_t stream) {
    const float* nfeat    = (const float*)d_in[0];
    const float* fc_w     = (const float*)d_in[1];
    const float* fc_e_w   = (const float*)d_in[2];
    const float* attn_l   = (const float*)d_in[3];
    const float* attn_r   = (const float*)d_in[4];
    const float* attn_e   = (const float*)d_in[5];
    const float* edge_emb = (const float*)d_in[6];
    const int*   src      = (const int*)d_in[7];
    const int*   dst      = (const int*)d_in[8];
    const int*   etype    = (const int*)d_in[9];

    float* ws = (float*)d_ws;
    ushort_t* feat = (ushort_t*)(ws + FEATBF_OFF);
    float* el   = ws + EL_OFF;
    float* er   = ws + ER_OFF;
    float* ee   = ws + EE_OFF;
    ushort_t* Bt = (ushort_t*)(ws + BT_OFF);
    int*   ip      = (int*)(ws + INT_OFF);
    int*   deg     = ip + DEG_IOFF;
    int*   cursor  = ip + CURSOR_IOFF;
    int*   rl      = ip + RL_IOFF;
    u64*   pk      = (u64*)(ip + PK_IOFF);
    int*   bo      = ip + BO_IOFF;

    float* rst   = (float*)d_out;                              // [N,H,F]
    float* a_out = (float*)d_out + (size_t)N_NODES * HF;       // [E,H]

    // K1: ee (1 blk) + cast_w (256) + zero deg/cursor (391)
    k1_prep<<<648, 256, 0, stream>>>(edge_emb, fc_e_w, attn_e, fc_w, ee, Bt, deg);
    // K2: int4 histogram || GEMM chunk
    k2_hist_gemm<<<NBLK_E4 + G2, 256, 0, stream>>>(
        nfeat, Bt, attn_l, attn_r, feat, el, er, dst, deg);
    // K3a/K3b: two-level scan || GEMM chunks
    scanA_gemm<<<NCHUNK + G3A, 256, 0, stream>>>(
        nfeat, Bt, attn_l, attn_r, feat, el, er, deg, rl, bo);
    scanB_gemm<<<1 + G3B, 256, 0, stream>>>(
        nfeat, Bt, attn_l, attn_r, feat, el, er, bo);
    // K4: int4 scatter || GEMM chunk
    k4_scatter_gemm<<<NBLK_E4 + G4, 256, 0, stream>>>(
        nfeat, Bt, attn_l, attn_r, feat, el, er,
        src, dst, etype, rl, bo, cursor, pk);
    // K5: wave-per-node softmax + aggregation
    agg_kernel<<<(N_NODES + 3) / 4, 256, 0, stream>>>(
        pk, rl, bo, deg, el, er, ee, feat, a_out, rst);
}

// Round 3
// 313.936 us; speedup vs baseline: 1.1907x; 1.1907x over previous
//
#include <hip/hip_runtime.h>

#define N_NODES 50000
#define E_EDGES 800000
#define IN_DIM 256
#define H_HEADS 4
#define F_OUT 64
#define EF_DIM 64
#define NT_TYPES 8
#define SLOPE 0.2f
#define HF 256  /* H*F */

typedef __attribute__((ext_vector_type(8))) short short8;
typedef __attribute__((ext_vector_type(4))) float f32x4;
typedef unsigned short ushort_t;
typedef unsigned long long u64;

// workspace layout (float element offsets)
#define FEATBF_OFF 0          /* N*HF bf16 = 6.4M floats */
#define EL_OFF   6400000
#define ER_OFF   6600000
#define EE_OFF   6800000
#define BT_OFF   6800064      /* 256x256 bf16 = 32768 floats */
#define INT_OFF  6832832
// int offsets within int region
#define DEG_IOFF     0        /* 50,000 */
#define CURSOR_IOFF  50000    /* 50,000 (adjacent: zeroed together by memset) */
#define RL_IOFF      100000   /* 50,000: per-node exclusive prefix within 256-chunk */
#define PK_IOFF      150008   /* packed edges: 800,000 u64 (8B aligned) */
#define BO_IOFF      1750008  /* 256: chunk-sum exclusive prefix (196 used) */

#define NBLK_GEMM 782         /* ceil(50000/64) */
#define NBLK_E4   782         /* ceil(800000/4/256): int4 edge kernels */
#define NCHUNK    196         /* ceil(50000/256) */

__device__ __forceinline__ ushort_t f2bf(float f) {
    unsigned u = __float_as_uint(f);
    u += 0x7fffu + ((u >> 16) & 1u);   // round-nearest-even
    return (ushort_t)(u >> 16);
}
__device__ __forceinline__ float bf2f(ushort_t b) {
    return __uint_as_float(((unsigned)b) << 16);
}

// ======================= K1: ee + cast_w + int4 histogram =======================
// deg/cursor are zeroed by hipMemsetAsync before this launch (stream-ordered).
__global__ __launch_bounds__(256) void k1_prep(
    const float* __restrict__ edge_emb, const float* __restrict__ fc_e_w,
    const float* __restrict__ attn_e, const float* __restrict__ fc_w,
    float* __restrict__ ee, ushort_t* __restrict__ Bt,
    const int* __restrict__ dst, int* __restrict__ deg)
{
    const int b = blockIdx.x;
    if (b == 0) {
        const int c = threadIdx.x;
        const float ae = attn_e[c];
        const int lane = c & 63, h = c >> 6;
        for (int ty = 0; ty < NT_TYPES; ty++) {
            float v = 0.f;
            #pragma unroll 8
            for (int k = 0; k < EF_DIM; k++)
                v = fmaf(edge_emb[ty * EF_DIM + k], fc_e_w[k * (H_HEADS * EF_DIM) + c], v);
            float contrib = v * ae;
            #pragma unroll
            for (int m = 32; m >= 1; m >>= 1) contrib += __shfl_xor(contrib, m);
            if (lane == 0) ee[ty * H_HEADS + h] = contrib;
        }
    } else if (b <= 256) {
        const int k = b - 1, c = threadIdx.x;
        Bt[(size_t)c * 256 + k] = f2bf(fc_w[(size_t)k * 256 + c]);
    } else {
        const int t = (b - 257) * 256 + threadIdx.x;
        if (t < E_EDGES / 4) {
            const int4 d4 = ((const int4*)dst)[t];
            atomicAdd(deg + d4.x, 1);
            atomicAdd(deg + d4.y, 1);
            atomicAdd(deg + d4.z, 1);
            atomicAdd(deg + d4.w, 1);
        }
    }
}

// ======================= K2a: per-chunk local scan (196 blocks) =======================
__global__ __launch_bounds__(256) void scanA(
    const int* __restrict__ deg, int* __restrict__ rl, int* __restrict__ bo)
{
    __shared__ int sm[256];
    const int c = blockIdx.x, t = threadIdx.x;
    const int g = c * 256 + t;
    const int v = (g < N_NODES) ? deg[g] : 0;
    sm[t] = v;
    __syncthreads();
    int val = v;
    #pragma unroll
    for (int o = 1; o < 256; o <<= 1) {
        int x = (t >= o) ? sm[t - o] : 0;
        __syncthreads();
        val += x;
        sm[t] = val;
        __syncthreads();
    }
    if (g < N_NODES) rl[g] = val - v;   // exclusive within chunk
    if (t == 255) bo[c] = val;          // chunk total
}

// ======================= K2b: scan chunk sums in place (1 tiny block) =======================
__global__ __launch_bounds__(256) void scanB(int* __restrict__ bo)
{
    __shared__ int sm[256];
    const int t = threadIdx.x;
    const int v = (t < NCHUNK) ? bo[t] : 0;
    sm[t] = v;
    __syncthreads();
    int val = v;
    #pragma unroll
    for (int o = 1; o < 256; o <<= 1) {
        int x = (t >= o) ? sm[t - o] : 0;
        __syncthreads();
        val += x;
        sm[t] = val;
        __syncthreads();
    }
    if (t < NCHUNK) bo[t] = val - v;    // exclusive chunk offsets
}

// ======================= GEMM body (MFMA bf16) =======================
__device__ __forceinline__ void gemm_body(
    const float* __restrict__ nfeat, const ushort_t* __restrict__ Bt,
    const float* __restrict__ attn_l, const float* __restrict__ attn_r,
    ushort_t* __restrict__ feat, float* __restrict__ el, float* __restrict__ er,
    int blk)
{
    const int w    = threadIdx.x >> 6;
    const int lane = threadIdx.x & 63;
    const int n16  = lane & 15;
    const int quad = lane >> 4;
    const int row0 = blk * 64;

    f32x4 acc[4][4];
    #pragma unroll
    for (int rt = 0; rt < 4; rt++)
        #pragma unroll
        for (int ct = 0; ct < 4; ct++)
            acc[rt][ct] = (f32x4){0.f, 0.f, 0.f, 0.f};

    for (int kb = 0; kb < IN_DIM; kb += 32) {
        short8 a[4], b[4];
        #pragma unroll
        for (int rt = 0; rt < 4; rt++) {
            int r = row0 + rt * 16 + n16;
            r = r < N_NODES ? r : N_NODES - 1;
            const float* p = nfeat + (size_t)r * IN_DIM + kb + quad * 8;
            const float4 v0 = *(const float4*)p;
            const float4 v1 = *(const float4*)(p + 4);
            short8 t;
            t[0] = (short)f2bf(v0.x); t[1] = (short)f2bf(v0.y);
            t[2] = (short)f2bf(v0.z); t[3] = (short)f2bf(v0.w);
            t[4] = (short)f2bf(v1.x); t[5] = (short)f2bf(v1.y);
            t[6] = (short)f2bf(v1.z); t[7] = (short)f2bf(v1.w);
            a[rt] = t;
        }
        #pragma unroll
        for (int ct = 0; ct < 4; ct++) {
            const int c = w * 64 + ct * 16 + n16;
            b[ct] = *(const short8*)(Bt + (size_t)c * 256 + kb + quad * 8);
        }
        #pragma unroll
        for (int rt = 0; rt < 4; rt++)
            #pragma unroll
            for (int ct = 0; ct < 4; ct++)
                acc[rt][ct] = __builtin_amdgcn_mfma_f32_16x16x32_bf16(a[rt], b[ct], acc[rt][ct], 0, 0, 0);
    }

    float alv[4], arv[4];
    #pragma unroll
    for (int ct = 0; ct < 4; ct++) {
        alv[ct] = attn_l[w * 64 + ct * 16 + n16];
        arv[ct] = attn_r[w * 64 + ct * 16 + n16];
    }
    #pragma unroll
    for (int rt = 0; rt < 4; rt++) {
        #pragma unroll
        for (int reg = 0; reg < 4; reg++) {
            const int row = row0 + rt * 16 + quad * 4 + reg;
            const bool ok = row < N_NODES;
            float pl = 0.f, pr = 0.f;
            #pragma unroll
            for (int ct = 0; ct < 4; ct++) {
                const float v = acc[rt][ct][reg];
                if (ok) feat[(size_t)row * HF + w * 64 + ct * 16 + n16] = f2bf(v);
                pl = fmaf(v, alv[ct], pl);
                pr = fmaf(v, arv[ct], pr);
            }
            #pragma unroll
            for (int m = 8; m >= 1; m >>= 1) {
                pl += __shfl_xor(pl, m);
                pr += __shfl_xor(pr, m);
            }
            if (n16 == 0 && ok) {
                el[row * H_HEADS + w] = pl;
                er[row * H_HEADS + w] = pr;
            }
        }
    }
}

// ======================= K3: full GEMM || int4 scatter (one big launch) =======================
__global__ __launch_bounds__(256) void k3_gemm_scatter(
    const float* __restrict__ nfeat, const ushort_t* __restrict__ Bt,
    const float* __restrict__ attn_l, const float* __restrict__ attn_r,
    ushort_t* __restrict__ feat, float* __restrict__ el, float* __restrict__ er,
    const int* __restrict__ src, const int* __restrict__ dst, const int* __restrict__ etype,
    const int* __restrict__ rl, const int* __restrict__ bo,
    int* __restrict__ cursor, u64* __restrict__ pk)
{
    if (blockIdx.x < NBLK_GEMM) {
        gemm_body(nfeat, Bt, attn_l, attn_r, feat, el, er, blockIdx.x);
    } else {
        const int t = ((int)blockIdx.x - NBLK_GEMM) * 256 + threadIdx.x;
        if (t < E_EDGES / 4) {
            const int4 s4 = ((const int4*)src)[t];
            const int4 d4 = ((const int4*)dst)[t];
            const int4 e4 = ((const int4*)etype)[t];
            const int eb = t * 4;
            int pos;
            pos = bo[d4.x >> 8] + rl[d4.x] + atomicAdd(cursor + d4.x, 1);
            pk[pos] = (u64)s4.x | ((u64)e4.x << 16) | ((u64)(eb + 0) << 32);
            pos = bo[d4.y >> 8] + rl[d4.y] + atomicAdd(cursor + d4.y, 1);
            pk[pos] = (u64)s4.y | ((u64)e4.y << 16) | ((u64)(eb + 1) << 32);
            pos = bo[d4.z >> 8] + rl[d4.z] + atomicAdd(cursor + d4.z, 1);
            pk[pos] = (u64)s4.z | ((u64)e4.z << 16) | ((u64)(eb + 2) << 32);
            pos = bo[d4.w >> 8] + rl[d4.w] + atomicAdd(cursor + d4.w, 1);
            pk[pos] = (u64)s4.w | ((u64)e4.w << 16) | ((u64)(eb + 3) << 32);
        }
    }
}

// ======================= agg fallback: any degree (correctness path) =======================
__device__ void agg_fallback(
    int d, int off, int deg, int h, int l,
    const u64* __restrict__ pk, const float* __restrict__ el,
    const float erh, const float* __restrict__ ee,
    const uint2* __restrict__ fb, float* __restrict__ a_out, float* __restrict__ rst)
{
    float m = -INFINITY;
    for (int i = l; i < deg; i += 16) {
        const u64 p = pk[off + i];
        float v = el[(int)(p & 0xffffu) * 4 + h] + erh + ee[(int)((p >> 16) & 0xffu) * 4 + h];
        v = v > 0.f ? v : SLOPE * v;
        m = fmaxf(m, v);
    }
    m = fmaxf(m, __shfl_xor(m, 1));
    m = fmaxf(m, __shfl_xor(m, 2));
    m = fmaxf(m, __shfl_xor(m, 4));
    m = fmaxf(m, __shfl_xor(m, 8));
    float s = 0.f;
    for (int i = l; i < deg; i += 16) {
        const u64 p = pk[off + i];
        float v = el[(int)(p & 0xffffu) * 4 + h] + erh + ee[(int)((p >> 16) & 0xffu) * 4 + h];
        v = v > 0.f ? v : SLOPE * v;
        s += __expf(v - m);
    }
    s += __shfl_xor(s, 1);
    s += __shfl_xor(s, 2);
    s += __shfl_xor(s, 4);
    s += __shfl_xor(s, 8);
    const float inv = 1.f / s;
    for (int i = l; i < deg; i += 16) {
        const u64 p = pk[off + i];
        const int sn = (int)(p & 0xffffu);
        float v = el[sn * 4 + h] + erh + ee[(int)((p >> 16) & 0xffu) * 4 + h];
        v = v > 0.f ? v : SLOPE * v;
        a_out[(int)(p >> 32) * 4 + h] = __expf(v - m) * inv;
    }
    float4 acc = {0.f, 0.f, 0.f, 0.f};
    const int col = h * 16 + l;
    for (int e = 0; e < deg; e++) {
        const u64 p = pk[off + e];
        const int sn = (int)(p & 0xffffu);
        float v = el[sn * 4 + h] + erh + ee[(int)((p >> 16) & 0xffu) * 4 + h];
        v = v > 0.f ? v : SLOPE * v;
        const float aw = __expf(v - m) * inv;
        const uint2 u = fb[(size_t)sn * 64 + col];
        acc.x = fmaf(aw, __uint_as_float(u.x << 16),         acc.x);
        acc.y = fmaf(aw, __uint_as_float(u.x & 0xffff0000u), acc.y);
        acc.z = fmaf(aw, __uint_as_float(u.y << 16),         acc.z);
        acc.w = fmaf(aw, __uint_as_float(u.y & 0xffff0000u), acc.w);
    }
    *(float4*)(rst + (size_t)d * HF + h * 64 + l * 4) = acc;
}

// ======================= K4: wave-per-2-nodes softmax + aggregation (v7) =======================
// Wave layout: 64 lanes = 4 head-groups x 16 edge-slots; wave owns nodes dA, dB.
// Paired phases double independent miss-chains; gather interleaves both nodes 8-deep.
__global__ __launch_bounds__(256) void agg_kernel(
    const u64* __restrict__ pk, const int* __restrict__ rl, const int* __restrict__ bo,
    const int* __restrict__ degarr,
    const float* __restrict__ el, const float* __restrict__ er,
    const float* __restrict__ ee, const ushort_t* __restrict__ feat,
    float* __restrict__ a_out, float* __restrict__ rst)
{
    const int wid  = threadIdx.x >> 6;
    const int lane = threadIdx.x & 63;
    const int h    = lane >> 4;
    const int l    = lane & 15;
    const int dA   = blockIdx.x * 8 + wid * 2;   // 6250*8 = 50000 exactly
    const int dB   = dA + 1;

    __shared__ __align__(16) float    sExp[4][2][256];  // [wave][node][edge*4+h]
    __shared__ __align__(16) ushort_t sSrc[4][2][64];

    float* expA = sExp[wid][0];
    float* expB = sExp[wid][1];
    ushort_t* srcA = sSrc[wid][0];
    ushort_t* srcB = sSrc[wid][1];
    const uint2* fb = (const uint2*)feat;

    const int offA = bo[dA >> 8] + rl[dA];
    const int offB = bo[dB >> 8] + rl[dB];
    const int degA = degarr[dA];
    const int degB = degarr[dB];
    const float erhA = er[dA * 4 + h];
    const float erhB = er[dB * 4 + h];
    const bool fsA = (degA <= 64);
    const bool fsB = (degB <= 64);
    const int nchA = fsA ? (degA + 15) >> 4 : 0;
    const int nchB = fsB ? (degB + 15) >> 4 : 0;
    const int ncm  = nchA > nchB ? nchA : nchB;

    // Phase A: leaky scores -> LDS raw; both nodes' pk loads issued per iteration
    float mA = -INFINITY, mB = -INFINITY;
    for (int c = 0; c < ncm; c++) {
        const int e = c * 16 + l;
        const bool inA = (c < nchA);
        const bool inB = (c < nchB);
        const bool ldA = inA && (e < degA);
        const bool ldB = inB && (e < degB);
        u64 pA = 0, pB = 0;
        if (ldA) pA = pk[offA + e];
        if (ldB) pB = pk[offB + e];
        if (inA) {
            float v = -INFINITY;
            if (ldA) {
                const int s  = (int)(pA & 0xffffu);
                const int ty = (int)((pA >> 16) & 0xffu);
                if (h == 0) srcA[e] = (ushort_t)s;
                v = el[s * 4 + h] + erhA + ee[ty * 4 + h];
                v = v > 0.f ? v : SLOPE * v;
                expA[e * 4 + h] = v;
            } else if (h == 0) srcA[e] = 0;   // pad -> row 0, weight 0
            mA = fmaxf(mA, v);
        }
        if (inB) {
            float v = -INFINITY;
            if (ldB) {
                const int s  = (int)(pB & 0xffffu);
                const int ty = (int)((pB >> 16) & 0xffu);
                if (h == 0) srcB[e] = (ushort_t)s;
                v = el[s * 4 + h] + erhB + ee[ty * 4 + h];
                v = v > 0.f ? v : SLOPE * v;
                expB[e * 4 + h] = v;
            } else if (h == 0) srcB[e] = 0;
            mB = fmaxf(mB, v);
        }
    }
    #pragma unroll
    for (int o = 8; o >= 1; o >>= 1) {
        mA = fmaxf(mA, __shfl_xor(mA, o));
        mB = fmaxf(mB, __shfl_xor(mB, o));
    }

    // Phase B: exp in place (pads -> 0), sum
    float sA = 0.f, sB = 0.f;
    for (int c = 0; c < nchA; c++) {
        const int e = c * 16 + l;
        float ev = 0.f;
        if (e < degA) ev = __expf(expA[e * 4 + h] - mA);
        expA[e * 4 + h] = ev;
        sA += ev;
    }
    for (int c = 0; c < nchB; c++) {
        const int e = c * 16 + l;
        float ev = 0.f;
        if (e < degB) ev = __expf(expB[e * 4 + h] - mB);
        expB[e * 4 + h] = ev;
        sB += ev;
    }
    #pragma unroll
    for (int o = 8; o >= 1; o >>= 1) {
        sA += __shfl_xor(sA, o);
        sB += __shfl_xor(sB, o);
    }
    const float invA = (degA > 0) ? 1.f / sA : 0.f;
    const float invB = (degB > 0) ? 1.f / sB : 0.f;

    // wave-level fence: LDS writes above visible to cross-lane reads below
    asm volatile("s_waitcnt lgkmcnt(0)" ::: "memory");

    const float iA0 = __shfl(invA, 0),  iA1 = __shfl(invA, 16);
    const float iA2 = __shfl(invA, 32), iA3 = __shfl(invA, 48);
    const float iB0 = __shfl(invB, 0),  iB1 = __shfl(invB, 16);
    const float iB2 = __shfl(invB, 32), iB3 = __shfl(invB, 48);

    // Phase C: a_out — group 0 writes node A, group 1 writes node B (parallel)
    if (h == 0) {
        for (int c = 0; c < nchA; c++) {
            const int e = c * 16 + l;
            if (e < degA) {
                const int eid = (int)(pk[offA + e] >> 32);   // L2-hot reload
                const float4 t = *(const float4*)(expA + e * 4);
                float4 av;
                av.x = t.x * iA0; av.y = t.y * iA1; av.z = t.z * iA2; av.w = t.w * iA3;
                *(float4*)(a_out + (size_t)eid * 4) = av;
            }
        }
    } else if (h == 1) {
        for (int c = 0; c < nchB; c++) {
            const int e = c * 16 + l;
            if (e < degB) {
                const int eid = (int)(pk[offB + e] >> 32);
                const float4 t = *(const float4*)(expB + e * 4);
                float4 av;
                av.x = t.x * iB0; av.y = t.y * iB1; av.z = t.z * iB2; av.w = t.w * iB3;
                *(float4*)(a_out + (size_t)eid * 4) = av;
            }
        }
    }

    // Phase D: interleaved gather, 8-deep per node (up to 16 loads in flight/lane)
    const int degPA = nchA << 4;
    const int degPB = nchB << 4;
    const int degPm = degPA > degPB ? degPA : degPB;
    const int col = h * 16 + l;
    float4 accA = {0.f, 0.f, 0.f, 0.f};
    float4 accB = {0.f, 0.f, 0.f, 0.f};
    for (int e0 = 0; e0 < degPm; e0 += 8) {
        const bool gA = e0 < degPA;
        const bool gB = e0 < degPB;
        uint2 uA[8], uB[8];
        float wA[8], wB[8];
        if (gA) {
            #pragma unroll
            for (int j = 0; j < 8; j++) {
                const int e = e0 + j;
                wA[j] = expA[e * 4 + h];
                uA[j] = fb[(size_t)srcA[e] * 64 + col];
            }
        }
        if (gB) {
            #pragma unroll
            for (int j = 0; j < 8; j++) {
                const int e = e0 + j;
                wB[j] = expB[e * 4 + h];
                uB[j] = fb[(size_t)srcB[e] * 64 + col];
            }
        }
        if (gA) {
            #pragma unroll
            for (int j = 0; j < 8; j++) {
                accA.x = fmaf(wA[j], __uint_as_float(uA[j].x << 16),         accA.x);
                accA.y = fmaf(wA[j], __uint_as_float(uA[j].x & 0xffff0000u), accA.y);
                accA.z = fmaf(wA[j], __uint_as_float(uA[j].y << 16),         accA.z);
                accA.w = fmaf(wA[j], __uint_as_float(uA[j].y & 0xffff0000u), accA.w);
            }
        }
        if (gB) {
            #pragma unroll
            for (int j = 0; j < 8; j++) {
                accB.x = fmaf(wB[j], __uint_as_float(uB[j].x << 16),         accB.x);
                accB.y = fmaf(wB[j], __uint_as_float(uB[j].x & 0xffff0000u), accB.y);
                accB.z = fmaf(wB[j], __uint_as_float(uB[j].y << 16),         accB.z);
                accB.w = fmaf(wB[j], __uint_as_float(uB[j].y & 0xffff0000u), accB.w);
            }
        }
    }
    if (fsA) {
        accA.x *= invA; accA.y *= invA; accA.z *= invA; accA.w *= invA;
        *(float4*)(rst + (size_t)dA * HF + h * 64 + l * 4) = accA;
    }
    if (fsB) {
        accB.x *= invB; accB.y *= invB; accB.z *= invB; accB.w *= invB;
        *(float4*)(rst + (size_t)dB * HF + h * 64 + l * 4) = accB;
    }
    // slow path (deg > 64): correctness only, never expected for this input
    if (!fsA) agg_fallback(dA, offA, degA, h, l, pk, el, erhA, ee, fb, a_out, rst);
    if (!fsB) agg_fallback(dB, offB, degB, h, l, pk, el, erhB, ee, fb, a_out, rst);
}

extern "C" void kernel_launch(void* const* d_in, const int* in_sizes, int n_in,
                              void* d_out, int out_size, void* d_ws, size_t ws_size,
                              hipStream_t stream) {
    const float* nfeat    = (const float*)d_in[0];
    const float* fc_w     = (const float*)d_in[1];
    const float* fc_e_w   = (const float*)d_in[2];
    const float* attn_l   = (const float*)d_in[3];
    const float* attn_r   = (const float*)d_in[4];
    const float* attn_e   = (const float*)d_in[5];
    const float* edge_emb = (const float*)d_in[6];
    const int*   src      = (const int*)d_in[7];
    const int*   dst      = (const int*)d_in[8];
    const int*   etype    = (const int*)d_in[9];

    float* ws = (float*)d_ws;
    ushort_t* feat = (ushort_t*)(ws + FEATBF_OFF);
    float* el   = ws + EL_OFF;
    float* er   = ws + ER_OFF;
    float* ee   = ws + EE_OFF;
    ushort_t* Bt = (ushort_t*)(ws + BT_OFF);
    int*   ip      = (int*)(ws + INT_OFF);
    int*   deg     = ip + DEG_IOFF;
    int*   cursor  = ip + CURSOR_IOFF;
    int*   rl      = ip + RL_IOFF;
    u64*   pk      = (u64*)(ip + PK_IOFF);
    int*   bo      = ip + BO_IOFF;

    float* rst   = (float*)d_out;                              // [N,H,F]
    float* a_out = (float*)d_out + (size_t)N_NODES * HF;       // [E,H]

    // zero deg+cursor via DMA (graph-capturable, stream-ordered)
    hipMemsetAsync(deg, 0, 2 * N_NODES * sizeof(int), stream);
    // K1: ee (1 blk) + cast Bt (256) + int4 hist (782)
    k1_prep<<<1039, 256, 0, stream>>>(edge_emb, fc_e_w, attn_e, fc_w, ee, Bt, dst, deg);
    // K2: two-level scan
    scanA<<<NCHUNK, 256, 0, stream>>>(deg, rl, bo);
    scanB<<<1, 256, 0, stream>>>(bo);
    // K3: full GEMM || int4 scatter (single launch keeps CUs saturated)
    k3_gemm_scatter<<<NBLK_GEMM + NBLK_E4, 256, 0, stream>>>(
        nfeat, Bt, attn_l, attn_r, feat, el, er,
        src, dst, etype, rl, bo, cursor, pk);
    // K4: wave-per-2-nodes softmax + aggregation
    agg_kernel<<<N_NODES / 8, 256, 0, stream>>>(
        pk, rl, bo, deg, el, er, ee, feat, a_out, rst);
}

// Round 4
// 298.335 us; speedup vs baseline: 1.2529x; 1.0523x over previous
//
#include <hip/hip_runtime.h>

#define N_NODES 50000
#define E_EDGES 800000
#define IN_DIM 256
#define H_HEADS 4
#define F_OUT 64
#define EF_DIM 64
#define NT_TYPES 8
#define SLOPE 0.2f
#define HF 256  /* H*F */

typedef __attribute__((ext_vector_type(8))) short short8;
typedef __attribute__((ext_vector_type(4))) float f32x4;
typedef unsigned short ushort_t;
typedef unsigned long long u64;

// workspace layout (float element offsets)
#define FEATBF_OFF 0          /* N*HF bf16 = 6.4M floats */
#define EL_OFF   6400000
#define ER_OFF   6600000
#define EE_OFF   6800000
#define BT_OFF   6800064      /* 256x256 bf16 = 32768 floats */
#define INT_OFF  6832832
// int offsets within int region
// deg is PADDED: one counter per 64B line -> deg[d*16], 50000*16 = 800,000 ints (3.2MB)
#define DEGP_IOFF    0
#define RL_IOFF      800000   /* 50,000: per-node exclusive prefix within 256-chunk */
#define BO_IOFF      850000   /* 256: chunk-sum exclusive prefix (196 used) */
#define RANK_IOFF    850256   /* 800,000 u16 = 400,000 ints (8B-aligned: 850256*4%8==0) */
#define PK_IOFF      1250256  /* packed edges: 800,000 u64 (8B aligned: even int offset) */

#define NBLK_GEMM 782         /* ceil(50000/64) */
#define NBLK_E1   3125        /* 800000/256: 1 edge/thread rank pass */
#define NBLK_E4   782         /* ceil(800000/4/256): int4 placement pass */
#define NCHUNK    196         /* ceil(50000/256) */

__device__ __forceinline__ ushort_t f2bf(float f) {
    unsigned u = __float_as_uint(f);
    u += 0x7fffu + ((u >> 16) & 1u);   // round-nearest-even
    return (ushort_t)(u >> 16);
}
__device__ __forceinline__ float bf2f(ushort_t b) {
    return __uint_as_float(((unsigned)b) << 16);
}

// ======================= K1: ee + cast_w (tiny) =======================
__global__ __launch_bounds__(256) void k1_prep(
    const float* __restrict__ edge_emb, const float* __restrict__ fc_e_w,
    const float* __restrict__ attn_e, const float* __restrict__ fc_w,
    float* __restrict__ ee, ushort_t* __restrict__ Bt)
{
    const int b = blockIdx.x;
    if (b == 0) {
        const int c = threadIdx.x;
        const float ae = attn_e[c];
        const int lane = c & 63, h = c >> 6;
        for (int ty = 0; ty < NT_TYPES; ty++) {
            float v = 0.f;
            #pragma unroll 8
            for (int k = 0; k < EF_DIM; k++)
                v = fmaf(edge_emb[ty * EF_DIM + k], fc_e_w[k * (H_HEADS * EF_DIM) + c], v);
            float contrib = v * ae;
            #pragma unroll
            for (int m = 32; m >= 1; m >>= 1) contrib += __shfl_xor(contrib, m);
            if (lane == 0) ee[ty * H_HEADS + h] = contrib;
        }
    } else {
        const int k = b - 1, c = threadIdx.x;
        Bt[(size_t)c * 256 + k] = f2bf(fc_w[(size_t)k * 256 + c]);
    }
}

// ======================= GEMM body (MFMA bf16) =======================
__device__ __forceinline__ void gemm_body(
    const float* __restrict__ nfeat, const ushort_t* __restrict__ Bt,
    const float* __restrict__ attn_l, const float* __restrict__ attn_r,
    ushort_t* __restrict__ feat, float* __restrict__ el, float* __restrict__ er,
    int blk)
{
    const int w    = threadIdx.x >> 6;
    const int lane = threadIdx.x & 63;
    const int n16  = lane & 15;
    const int quad = lane >> 4;
    const int row0 = blk * 64;

    f32x4 acc[4][4];
    #pragma unroll
    for (int rt = 0; rt < 4; rt++)
        #pragma unroll
        for (int ct = 0; ct < 4; ct++)
            acc[rt][ct] = (f32x4){0.f, 0.f, 0.f, 0.f};

    for (int kb = 0; kb < IN_DIM; kb += 32) {
        short8 a[4], b[4];
        #pragma unroll
        for (int rt = 0; rt < 4; rt++) {
            int r = row0 + rt * 16 + n16;
            r = r < N_NODES ? r : N_NODES - 1;
            const float* p = nfeat + (size_t)r * IN_DIM + kb + quad * 8;
            const float4 v0 = *(const float4*)p;
            const float4 v1 = *(const float4*)(p + 4);
            short8 t;
            t[0] = (short)f2bf(v0.x); t[1] = (short)f2bf(v0.y);
            t[2] = (short)f2bf(v0.z); t[3] = (short)f2bf(v0.w);
            t[4] = (short)f2bf(v1.x); t[5] = (short)f2bf(v1.y);
            t[6] = (short)f2bf(v1.z); t[7] = (short)f2bf(v1.w);
            a[rt] = t;
        }
        #pragma unroll
        for (int ct = 0; ct < 4; ct++) {
            const int c = w * 64 + ct * 16 + n16;
            b[ct] = *(const short8*)(Bt + (size_t)c * 256 + kb + quad * 8);
        }
        #pragma unroll
        for (int rt = 0; rt < 4; rt++)
            #pragma unroll
            for (int ct = 0; ct < 4; ct++)
                acc[rt][ct] = __builtin_amdgcn_mfma_f32_16x16x32_bf16(a[rt], b[ct], acc[rt][ct], 0, 0, 0);
    }

    float alv[4], arv[4];
    #pragma unroll
    for (int ct = 0; ct < 4; ct++) {
        alv[ct] = attn_l[w * 64 + ct * 16 + n16];
        arv[ct] = attn_r[w * 64 + ct * 16 + n16];
    }
    #pragma unroll
    for (int rt = 0; rt < 4; rt++) {
        #pragma unroll
        for (int reg = 0; reg < 4; reg++) {
            const int row = row0 + rt * 16 + quad * 4 + reg;
            const bool ok = row < N_NODES;
            float pl = 0.f, pr = 0.f;
            #pragma unroll
            for (int ct = 0; ct < 4; ct++) {
                const float v = acc[rt][ct][reg];
                if (ok) feat[(size_t)row * HF + w * 64 + ct * 16 + n16] = f2bf(v);
                pl = fmaf(v, alv[ct], pl);
                pr = fmaf(v, arv[ct], pr);
            }
            #pragma unroll
            for (int m = 8; m >= 1; m >>= 1) {
                pl += __shfl_xor(pl, m);
                pr += __shfl_xor(pr, m);
            }
            if (n16 == 0 && ok) {
                el[row * H_HEADS + w] = pl;
                er[row * H_HEADS + w] = pr;
            }
        }
    }
}

// ======================= K2: full GEMM || rank pass (single atomic pass) =======================
// rank[e] = old count = within-dst rank; final deg[d*16] = degree. One pass does
// the work of histogram + cursor. deg padded to 1 counter / 64B line.
__global__ __launch_bounds__(256) void k2_gemm_rank(
    const float* __restrict__ nfeat, const ushort_t* __restrict__ Bt,
    const float* __restrict__ attn_l, const float* __restrict__ attn_r,
    ushort_t* __restrict__ feat, float* __restrict__ el, float* __restrict__ er,
    const int* __restrict__ dst, int* __restrict__ degp, ushort_t* __restrict__ rank)
{
    if (blockIdx.x < NBLK_GEMM) {
        gemm_body(nfeat, Bt, attn_l, attn_r, feat, el, er, blockIdx.x);
    } else {
        const int e = ((int)blockIdx.x - NBLK_GEMM) * 256 + threadIdx.x;  // 3125*256 = 800000 exact
        const int d = dst[e];
        rank[e] = (ushort_t)atomicAdd(degp + (d << 4), 1);
    }
}

// ======================= K3a: per-chunk local scan (196 blocks, strided deg) =======================
__global__ __launch_bounds__(256) void scanA(
    const int* __restrict__ degp, int* __restrict__ rl, int* __restrict__ bo)
{
    __shared__ int sm[256];
    const int c = blockIdx.x, t = threadIdx.x;
    const int g = c * 256 + t;
    const int v = (g < N_NODES) ? degp[g << 4] : 0;
    sm[t] = v;
    __syncthreads();
    int val = v;
    #pragma unroll
    for (int o = 1; o < 256; o <<= 1) {
        int x = (t >= o) ? sm[t - o] : 0;
        __syncthreads();
        val += x;
        sm[t] = val;
        __syncthreads();
    }
    if (g < N_NODES) rl[g] = val - v;   // exclusive within chunk
    if (t == 255) bo[c] = val;          // chunk total
}

// ======================= K3b: scan chunk sums in place (1 tiny block) =======================
__global__ __launch_bounds__(256) void scanB(int* __restrict__ bo)
{
    __shared__ int sm[256];
    const int t = threadIdx.x;
    const int v = (t < NCHUNK) ? bo[t] : 0;
    sm[t] = v;
    __syncthreads();
    int val = v;
    #pragma unroll
    for (int o = 1; o < 256; o <<= 1) {
        int x = (t >= o) ? sm[t - o] : 0;
        __syncthreads();
        val += x;
        sm[t] = val;
        __syncthreads();
    }
    if (t < NCHUNK) bo[t] = val - v;    // exclusive chunk offsets
}

// ======================= K4: placement pass — ZERO atomics, pure streaming =======================
__global__ __launch_bounds__(256) void k4_place(
    const int* __restrict__ src, const int* __restrict__ dst, const int* __restrict__ etype,
    const ushort_t* __restrict__ rank,
    const int* __restrict__ rl, const int* __restrict__ bo, u64* __restrict__ pk)
{
    const int t = blockIdx.x * 256 + threadIdx.x;
    if (t >= E_EDGES / 4) return;
    const int4 s4 = ((const int4*)src)[t];
    const int4 d4 = ((const int4*)dst)[t];
    const int4 e4 = ((const int4*)etype)[t];
    const ushort4 r4 = ((const ushort4*)rank)[t];
    const int eb = t * 4;
    int pos;
    pos = bo[d4.x >> 8] + rl[d4.x] + (int)r4.x;
    pk[pos] = (u64)s4.x | ((u64)e4.x << 16) | ((u64)(eb + 0) << 32);
    pos = bo[d4.y >> 8] + rl[d4.y] + (int)r4.y;
    pk[pos] = (u64)s4.y | ((u64)e4.y << 16) | ((u64)(eb + 1) << 32);
    pos = bo[d4.z >> 8] + rl[d4.z] + (int)r4.z;
    pk[pos] = (u64)s4.z | ((u64)e4.z << 16) | ((u64)(eb + 2) << 32);
    pos = bo[d4.w >> 8] + rl[d4.w] + (int)r4.w;
    pk[pos] = (u64)s4.w | ((u64)e4.w << 16) | ((u64)(eb + 3) << 32);
}

// ======================= agg fallback: any degree (correctness path) =======================
__device__ void agg_fallback(
    int d, int off, int deg, int h, int l,
    const u64* __restrict__ pk, const float* __restrict__ el,
    const float erh, const float* __restrict__ ee,
    const uint2* __restrict__ fb, float* __restrict__ a_out, float* __restrict__ rst)
{
    float m = -INFINITY;
    for (int i = l; i < deg; i += 16) {
        const u64 p = pk[off + i];
        float v = el[(int)(p & 0xffffu) * 4 + h] + erh + ee[(int)((p >> 16) & 0xffu) * 4 + h];
        v = v > 0.f ? v : SLOPE * v;
        m = fmaxf(m, v);
    }
    m = fmaxf(m, __shfl_xor(m, 1));
    m = fmaxf(m, __shfl_xor(m, 2));
    m = fmaxf(m, __shfl_xor(m, 4));
    m = fmaxf(m, __shfl_xor(m, 8));
    float s = 0.f;
    for (int i = l; i < deg; i += 16) {
        const u64 p = pk[off + i];
        float v = el[(int)(p & 0xffffu) * 4 + h] + erh + ee[(int)((p >> 16) & 0xffu) * 4 + h];
        v = v > 0.f ? v : SLOPE * v;
        s += __expf(v - m);
    }
    s += __shfl_xor(s, 1);
    s += __shfl_xor(s, 2);
    s += __shfl_xor(s, 4);
    s += __shfl_xor(s, 8);
    const float inv = 1.f / s;
    for (int i = l; i < deg; i += 16) {
        const u64 p = pk[off + i];
        const int sn = (int)(p & 0xffffu);
        float v = el[sn * 4 + h] + erh + ee[(int)((p >> 16) & 0xffu) * 4 + h];
        v = v > 0.f ? v : SLOPE * v;
        a_out[(int)(p >> 32) * 4 + h] = __expf(v - m) * inv;
    }
    float4 acc = {0.f, 0.f, 0.f, 0.f};
    const int col = h * 16 + l;
    for (int e = 0; e < deg; e++) {
        const u64 p = pk[off + e];
        const int sn = (int)(p & 0xffffu);
        float v = el[sn * 4 + h] + erh + ee[(int)((p >> 16) & 0xffu) * 4 + h];
        v = v > 0.f ? v : SLOPE * v;
        const float aw = __expf(v - m) * inv;
        const uint2 u = fb[(size_t)sn * 64 + col];
        acc.x = fmaf(aw, __uint_as_float(u.x << 16),         acc.x);
        acc.y = fmaf(aw, __uint_as_float(u.x & 0xffff0000u), acc.y);
        acc.z = fmaf(aw, __uint_as_float(u.y << 16),         acc.z);
        acc.w = fmaf(aw, __uint_as_float(u.y & 0xffff0000u), acc.w);
    }
    *(float4*)(rst + (size_t)d * HF + h * 64 + l * 4) = acc;
}

// ======================= K5: wave-per-2-nodes softmax + aggregation (v7) =======================
__global__ __launch_bounds__(256) void agg_kernel(
    const u64* __restrict__ pk, const int* __restrict__ rl, const int* __restrict__ bo,
    const int* __restrict__ degp,
    const float* __restrict__ el, const float* __restrict__ er,
    const float* __restrict__ ee, const ushort_t* __restrict__ feat,
    float* __restrict__ a_out, float* __restrict__ rst)
{
    const int wid  = threadIdx.x >> 6;
    const int lane = threadIdx.x & 63;
    const int h    = lane >> 4;
    const int l    = lane & 15;
    const int dA   = blockIdx.x * 8 + wid * 2;   // 6250*8 = 50000 exactly
    const int dB   = dA + 1;

    __shared__ __align__(16) float    sExp[4][2][256];  // [wave][node][edge*4+h]
    __shared__ __align__(16) ushort_t sSrc[4][2][64];

    float* expA = sExp[wid][0];
    float* expB = sExp[wid][1];
    ushort_t* srcA = sSrc[wid][0];
    ushort_t* srcB = sSrc[wid][1];
    const uint2* fb = (const uint2*)feat;

    const int offA = bo[dA >> 8] + rl[dA];
    const int offB = bo[dB >> 8] + rl[dB];
    const int degA = degp[dA << 4];
    const int degB = degp[dB << 4];
    const float erhA = er[dA * 4 + h];
    const float erhB = er[dB * 4 + h];
    const bool fsA = (degA <= 64);
    const bool fsB = (degB <= 64);
    const int nchA = fsA ? (degA + 15) >> 4 : 0;
    const int nchB = fsB ? (degB + 15) >> 4 : 0;
    const int ncm  = nchA > nchB ? nchA : nchB;

    // Phase A: leaky scores -> LDS raw; both nodes' pk loads issued per iteration
    float mA = -INFINITY, mB = -INFINITY;
    for (int c = 0; c < ncm; c++) {
        const int e = c * 16 + l;
        const bool inA = (c < nchA);
        const bool inB = (c < nchB);
        const bool ldA = inA && (e < degA);
        const bool ldB = inB && (e < degB);
        u64 pA = 0, pB = 0;
        if (ldA) pA = pk[offA + e];
        if (ldB) pB = pk[offB + e];
        if (inA) {
            float v = -INFINITY;
            if (ldA) {
                const int s  = (int)(pA & 0xffffu);
                const int ty = (int)((pA >> 16) & 0xffu);
                if (h == 0) srcA[e] = (ushort_t)s;
                v = el[s * 4 + h] + erhA + ee[ty * 4 + h];
                v = v > 0.f ? v : SLOPE * v;
                expA[e * 4 + h] = v;
            } else if (h == 0) srcA[e] = 0;   // pad -> row 0, weight 0
            mA = fmaxf(mA, v);
        }
        if (inB) {
            float v = -INFINITY;
            if (ldB) {
                const int s  = (int)(pB & 0xffffu);
                const int ty = (int)((pB >> 16) & 0xffu);
                if (h == 0) srcB[e] = (ushort_t)s;
                v = el[s * 4 + h] + erhB + ee[ty * 4 + h];
                v = v > 0.f ? v : SLOPE * v;
                expB[e * 4 + h] = v;
            } else if (h == 0) srcB[e] = 0;
            mB = fmaxf(mB, v);
        }
    }
    #pragma unroll
    for (int o = 8; o >= 1; o >>= 1) {
        mA = fmaxf(mA, __shfl_xor(mA, o));
        mB = fmaxf(mB, __shfl_xor(mB, o));
    }

    // Phase B: exp in place (pads -> 0), sum
    float sA = 0.f, sB = 0.f;
    for (int c = 0; c < nchA; c++) {
        const int e = c * 16 + l;
        float ev = 0.f;
        if (e < degA) ev = __expf(expA[e * 4 + h] - mA);
        expA[e * 4 + h] = ev;
        sA += ev;
    }
    for (int c = 0; c < nchB; c++) {
        const int e = c * 16 + l;
        float ev = 0.f;
        if (e < degB) ev = __expf(expB[e * 4 + h] - mB);
        expB[e * 4 + h] = ev;
        sB += ev;
    }
    #pragma unroll
    for (int o = 8; o >= 1; o >>= 1) {
        sA += __shfl_xor(sA, o);
        sB += __shfl_xor(sB, o);
    }
    const float invA = (degA > 0) ? 1.f / sA : 0.f;
    const float invB = (degB > 0) ? 1.f / sB : 0.f;

    // wave-level fence: LDS writes above visible to cross-lane reads below
    asm volatile("s_waitcnt lgkmcnt(0)" ::: "memory");

    const float iA0 = __shfl(invA, 0),  iA1 = __shfl(invA, 16);
    const float iA2 = __shfl(invA, 32), iA3 = __shfl(invA, 48);
    const float iB0 = __shfl(invB, 0),  iB1 = __shfl(invB, 16);
    const float iB2 = __shfl(invB, 32), iB3 = __shfl(invB, 48);

    // Phase C: a_out — group 0 writes node A, group 1 writes node B (parallel)
    if (h == 0) {
        for (int c = 0; c < nchA; c++) {
            const int e = c * 16 + l;
            if (e < degA) {
                const int eid = (int)(pk[offA + e] >> 32);   // L2-hot reload
                const float4 t = *(const float4*)(expA + e * 4);
                float4 av;
                av.x = t.x * iA0; av.y = t.y * iA1; av.z = t.z * iA2; av.w = t.w * iA3;
                *(float4*)(a_out + (size_t)eid * 4) = av;
            }
        }
    } else if (h == 1) {
        for (int c = 0; c < nchB; c++) {
            const int e = c * 16 + l;
            if (e < degB) {
                const int eid = (int)(pk[offB + e] >> 32);
                const float4 t = *(const float4*)(expB + e * 4);
                float4 av;
                av.x = t.x * iB0; av.y = t.y * iB1; av.z = t.z * iB2; av.w = t.w * iB3;
                *(float4*)(a_out + (size_t)eid * 4) = av;
            }
        }
    }

    // Phase D: interleaved gather, 8-deep per node (up to 16 loads in flight/lane)
    const int degPA = nchA << 4;
    const int degPB = nchB << 4;
    const int degPm = degPA > degPB ? degPA : degPB;
    const int col = h * 16 + l;
    float4 accA = {0.f, 0.f, 0.f, 0.f};
    float4 accB = {0.f, 0.f, 0.f, 0.f};
    for (int e0 = 0; e0 < degPm; e0 += 8) {
        const bool gA = e0 < degPA;
        const bool gB = e0 < degPB;
        uint2 uA[8], uB[8];
        float wA[8], wB[8];
        if (gA) {
            #pragma unroll
            for (int j = 0; j < 8; j++) {
                const int e = e0 + j;
                wA[j] = expA[e * 4 + h];
                uA[j] = fb[(size_t)srcA[e] * 64 + col];
            }
        }
        if (gB) {
            #pragma unroll
            for (int j = 0; j < 8; j++) {
                const int e = e0 + j;
                wB[j] = expB[e * 4 + h];
                uB[j] = fb[(size_t)srcB[e] * 64 + col];
            }
        }
        if (gA) {
            #pragma unroll
            for (int j = 0; j < 8; j++) {
                accA.x = fmaf(wA[j], __uint_as_float(uA[j].x << 16),         accA.x);
                accA.y = fmaf(wA[j], __uint_as_float(uA[j].x & 0xffff0000u), accA.y);
                accA.z = fmaf(wA[j], __uint_as_float(uA[j].y << 16),         accA.z);
                accA.w = fmaf(wA[j], __uint_as_float(uA[j].y & 0xffff0000u), accA.w);
            }
        }
        if (gB) {
            #pragma unroll
            for (int j = 0; j < 8; j++) {
                accB.x = fmaf(wB[j], __uint_as_float(uB[j].x << 16),         accB.x);
                accB.y = fmaf(wB[j], __uint_as_float(uB[j].x & 0xffff0000u), accB.y);
                accB.z = fmaf(wB[j], __uint_as_float(uB[j].y << 16),         accB.z);
                accB.w = fmaf(wB[j], __uint_as_float(uB[j].y & 0xffff0000u), accB.w);
            }
        }
    }
    if (fsA) {
        accA.x *= invA; accA.y *= invA; accA.z *= invA; accA.w *= invA;
        *(float4*)(rst + (size_t)dA * HF + h * 64 + l * 4) = accA;
    }
    if (fsB) {
        accB.x *= invB; accB.y *= invB; accB.z *= invB; accB.w *= invB;
        *(float4*)(rst + (size_t)dB * HF + h * 64 + l * 4) = accB;
    }
    // slow path (deg > 64): correctness only, never expected for this input
    if (!fsA) agg_fallback(dA, offA, degA, h, l, pk, el, erhA, ee, fb, a_out, rst);
    if (!fsB) agg_fallback(dB, offB, degB, h, l, pk, el, erhB, ee, fb, a_out, rst);
}

extern "C" void kernel_launch(void* const* d_in, const int* in_sizes, int n_in,
                              void* d_out, int out_size, void* d_ws, size_t ws_size,
                              hipStream_t stream) {
    const float* nfeat    = (const float*)d_in[0];
    const float* fc_w     = (const float*)d_in[1];
    const float* fc_e_w   = (const float*)d_in[2];
    const float* attn_l   = (const float*)d_in[3];
    const float* attn_r   = (const float*)d_in[4];
    const float* attn_e   = (const float*)d_in[5];
    const float* edge_emb = (const float*)d_in[6];
    const int*   src      = (const int*)d_in[7];
    const int*   dst      = (const int*)d_in[8];
    const int*   etype    = (const int*)d_in[9];

    float* ws = (float*)d_ws;
    ushort_t* feat = (ushort_t*)(ws + FEATBF_OFF);
    float* el   = ws + EL_OFF;
    float* er   = ws + ER_OFF;
    float* ee   = ws + EE_OFF;
    ushort_t* Bt = (ushort_t*)(ws + BT_OFF);
    int*   ip      = (int*)(ws + INT_OFF);
    int*   degp    = ip + DEGP_IOFF;
    int*   rl      = ip + RL_IOFF;
    int*   bo      = ip + BO_IOFF;
    ushort_t* rank = (ushort_t*)(ip + RANK_IOFF);
    u64*   pk      = (u64*)(ip + PK_IOFF);

    float* rst   = (float*)d_out;                              // [N,H,F]
    float* a_out = (float*)d_out + (size_t)N_NODES * HF;       // [E,H]

    // zero padded deg (3.2MB) via DMA
    hipMemsetAsync(degp, 0, (size_t)N_NODES * 16 * sizeof(int), stream);
    // K1: ee (1 blk) + cast Bt (256) — tiny
    k1_prep<<<257, 256, 0, stream>>>(edge_emb, fc_e_w, attn_e, fc_w, ee, Bt);
    // K2: full GEMM || single-atomic-pass rank (hist+cursor fused)
    k2_gemm_rank<<<NBLK_GEMM + NBLK_E1, 256, 0, stream>>>(
        nfeat, Bt, attn_l, attn_r, feat, el, er, dst, degp, rank);
    // K3: two-level scan
    scanA<<<NCHUNK, 256, 0, stream>>>(degp, rl, bo);
    scanB<<<1, 256, 0, stream>>>(bo);
    // K4: placement — zero atomics, pure streaming
    k4_place<<<NBLK_E4, 256, 0, stream>>>(src, dst, etype, rank, rl, bo, pk);
    // K5: wave-per-2-nodes softmax + aggregation
    agg_kernel<<<N_NODES / 8, 256, 0, stream>>>(
        pk, rl, bo, degp, el, er, ee, feat, a_out, rst);
}